// Round 1
// baseline (180.399 us; speedup 1.0000x reference)
//
#include <hip/hip_runtime.h>

#define NN 10000
#define NE 640000
#define DIM 128

// ---------------------------------------------------------------------------
// z = h @ W_fc^T  (z[i][j] = sum_k h[i][k] * W[j][k]),  e[i] = z[i,:] . a_src
// W transposed into LDS with +1 padding (stride 129 -> bank (k+j)&31, conflict-free).
// ---------------------------------------------------------------------------
__global__ __launch_bounds__(128) void fc_kernel(
    const float* __restrict__ h, const float* __restrict__ W,
    const float* __restrict__ Wa, float* __restrict__ z,
    float* __restrict__ e, int n)
{
    __shared__ float Wt[128 * 129];
    __shared__ float hs[128];
    __shared__ float red[2];
    const int t = threadIdx.x;

    for (int idx = t; idx < 128 * 128; idx += 128) {
        int j = idx >> 7, k = idx & 127;
        Wt[k * 129 + j] = W[idx];
    }
    const float asrc = Wa[t];          // a_src = W_attn[0, :128]
    __syncthreads();

    for (int i = blockIdx.x; i < n; i += gridDim.x) {
        hs[t] = h[(size_t)i * DIM + t];
        __syncthreads();
        float acc = 0.f;
        const float4* h4 = (const float4*)hs;
        #pragma unroll
        for (int k4 = 0; k4 < 32; ++k4) {
            float4 hv = h4[k4];        // broadcast b128 read
            int k = k4 * 4;
            acc += hv.x * Wt[(k + 0) * 129 + t];
            acc += hv.y * Wt[(k + 1) * 129 + t];
            acc += hv.z * Wt[(k + 2) * 129 + t];
            acc += hv.w * Wt[(k + 3) * 129 + t];
        }
        z[(size_t)i * DIM + t] = acc;

        float ev = acc * asrc;         // reduce over 128 threads -> e[i]
        #pragma unroll
        for (int o = 32; o > 0; o >>= 1) ev += __shfl_down(ev, o, 64);
        if ((t & 63) == 0) red[t >> 6] = ev;
        __syncthreads();
        if (t == 0) e[i] = red[0] + red[1];
        __syncthreads();               // guards hs/red overwrite next iter
    }
}

// ---------------------------------------------------------------------------
// CSR build: histogram of dst -> exclusive scan -> scatter src by dst
// ---------------------------------------------------------------------------
__global__ void hist_kernel(const int* __restrict__ dst, int* __restrict__ cnt, int n)
{
    int i = blockIdx.x * blockDim.x + threadIdx.x;
    if (i < n) atomicAdd(&cnt[dst[i]], 1);
}

__global__ __launch_bounds__(1024) void scan_kernel(
    const int* __restrict__ cnt, int* __restrict__ offs, int* __restrict__ cur, int n)
{
    __shared__ int part[1024];
    const int t = threadIdx.x;
    constexpr int C = 10;              // 1024*10 >= 10000
    int loc[C];
    int base = t * C, s = 0;
    #pragma unroll
    for (int j = 0; j < C; ++j) {
        int idx = base + j;
        int v = (idx < n) ? cnt[idx] : 0;
        loc[j] = s; s += v;
    }
    part[t] = s;
    __syncthreads();
    for (int off = 1; off < 1024; off <<= 1) {   // Hillis-Steele inclusive scan
        int v = (t >= off) ? part[t - off] : 0;
        __syncthreads();
        if (t >= off) part[t] += v;
        __syncthreads();
    }
    int pre = (t == 0) ? 0 : part[t - 1];
    #pragma unroll
    for (int j = 0; j < C; ++j) {
        int idx = base + j;
        if (idx < n) { int o = pre + loc[j]; offs[idx] = o; cur[idx] = o; }
    }
    if (t == 1023) offs[n] = part[1023];
}

__global__ void scatter_kernel(const int* __restrict__ src, const int* __restrict__ dst,
                               int* __restrict__ cur, int* __restrict__ esrc, int n)
{
    int i = blockIdx.x * blockDim.x + threadIdx.x;
    if (i < n) {
        int p = atomicAdd(&cur[dst[i]], 1);
        esrc[p] = src[i];
    }
}

// ---------------------------------------------------------------------------
// Per-node softmax + aggregate. One 128-thread block per dst node; thread t
// owns output dim t. f[dst] cancels inside the per-segment softmax, so the
// attention weight is exp(e[src]-max)/sum(exp(e[src]-max)).
// ---------------------------------------------------------------------------
__global__ __launch_bounds__(128) void agg_kernel(
    const int* __restrict__ offs, const int* __restrict__ esrc,
    const float* __restrict__ e, const float* __restrict__ z,
    float* __restrict__ out)
{
    __shared__ float rbuf[2];
    const int v = blockIdx.x;
    const int t = threadIdx.x;
    const int beg = offs[v], end = offs[v + 1];

    // pass 1: max of e[src] over this node's in-edges
    float lm = -3.4e38f;
    for (int i = beg + t; i < end; i += 128) lm = fmaxf(lm, e[esrc[i]]);
    #pragma unroll
    for (int o = 32; o > 0; o >>= 1) lm = fmaxf(lm, __shfl_xor(lm, o, 64));
    if ((t & 63) == 0) rbuf[t >> 6] = lm;
    __syncthreads();
    const float mx = fmaxf(rbuf[0], rbuf[1]);
    __syncthreads();

    // pass 2: denominator
    float ls = 0.f;
    for (int i = beg + t; i < end; i += 128) ls += __expf(e[esrc[i]] - mx);
    #pragma unroll
    for (int o = 32; o > 0; o >>= 1) ls += __shfl_xor(ls, o, 64);
    if ((t & 63) == 0) rbuf[t >> 6] = ls;
    __syncthreads();
    const float den = rbuf[0] + rbuf[1];
    const float inv = (den > 0.f) ? (1.f / den) : 0.f;

    // pass 3: out[v][t] = sum_i alpha_i * z[src_i][t]  (coalesced 512B row reads)
    float a0 = 0.f, a1 = 0.f, a2 = 0.f, a3 = 0.f;
    int i = beg;
    for (; i + 3 < end; i += 4) {
        int s0 = esrc[i], s1 = esrc[i + 1], s2 = esrc[i + 2], s3 = esrc[i + 3];
        float w0 = __expf(e[s0] - mx) * inv;
        float w1 = __expf(e[s1] - mx) * inv;
        float w2 = __expf(e[s2] - mx) * inv;
        float w3 = __expf(e[s3] - mx) * inv;
        a0 += w0 * z[(size_t)s0 * DIM + t];
        a1 += w1 * z[(size_t)s1 * DIM + t];
        a2 += w2 * z[(size_t)s2 * DIM + t];
        a3 += w3 * z[(size_t)s3 * DIM + t];
    }
    for (; i < end; ++i) {
        int s = esrc[i];
        a0 += __expf(e[s] - mx) * inv * z[(size_t)s * DIM + t];
    }
    out[(size_t)v * DIM + t] = (end > beg) ? ((a0 + a1) + (a2 + a3)) : 0.f;
}

// ---------------------------------------------------------------------------
extern "C" void kernel_launch(void* const* d_in, const int* in_sizes, int n_in,
                              void* d_out, int out_size, void* d_ws, size_t ws_size,
                              hipStream_t stream)
{
    const float* h     = (const float*)d_in[0];
    const int*   src   = (const int*)d_in[1];
    const int*   dst   = (const int*)d_in[2];
    const float* Wfc   = (const float*)d_in[3];
    const float* Wattn = (const float*)d_in[4];
    float* out = (float*)d_out;

    // workspace layout (floats/ints, generous padding): ~7.9 MB total
    float* z    = (float*)d_ws;                 // 1,280,000 f32
    float* e    = z + (size_t)NN * DIM;         // 10,000 f32
    int*   cnt  = (int*)(e + 10016);            // 10,000 int
    int*   offs = cnt + 10016;                  // 10,001 int
    int*   cur  = offs + 10016;                 // 10,000 int
    int*   esrc = cur + 10016;                  // 640,000 int

    hipMemsetAsync(cnt, 0, NN * sizeof(int), stream);
    fc_kernel<<<1024, 128, 0, stream>>>(h, Wfc, Wattn, z, e, NN);
    hist_kernel<<<(NE + 255) / 256, 256, 0, stream>>>(dst, cnt, NE);
    scan_kernel<<<1, 1024, 0, stream>>>(cnt, offs, cur, NN);
    scatter_kernel<<<(NE + 255) / 256, 256, 0, stream>>>(src, dst, cur, esrc, NE);
    agg_kernel<<<NN, 128, 0, stream>>>(offs, esrc, e, z, out);
}

// Round 2
// 143.463 us; speedup vs baseline: 1.2575x; 1.2575x over previous
//
#include <hip/hip_runtime.h>

#define NN 10000
#define NE 640000
#define DIM 128
#define NB 64                         // histogram blocks for CSR build
#define EPB ((NE + NB - 1) / NB)      // edges per block = 10000

// ---------------------------------------------------------------------------
// z = h @ W_fc^T  (z[i][j] = sum_k h[i][k] * W[j][k]),  e[i] = z[i,:] . a_src
// W transposed into LDS with +1 padding (stride 129 -> conflict-free).
// ---------------------------------------------------------------------------
__global__ __launch_bounds__(128) void fc_kernel(
    const float* __restrict__ h, const float* __restrict__ W,
    const float* __restrict__ Wa, float* __restrict__ z,
    float* __restrict__ e, int n)
{
    __shared__ float Wt[128 * 129];
    __shared__ float hs[128];
    __shared__ float red[2];
    const int t = threadIdx.x;

    for (int idx = t; idx < 128 * 128; idx += 128) {
        int j = idx >> 7, k = idx & 127;
        Wt[k * 129 + j] = W[idx];
    }
    const float asrc = Wa[t];          // a_src = W_attn[0, :128]
    __syncthreads();

    for (int i = blockIdx.x; i < n; i += gridDim.x) {
        hs[t] = h[(size_t)i * DIM + t];
        __syncthreads();
        float acc = 0.f;
        const float4* h4 = (const float4*)hs;
        #pragma unroll
        for (int k4 = 0; k4 < 32; ++k4) {
            float4 hv = h4[k4];        // broadcast b128 read
            int k = k4 * 4;
            acc += hv.x * Wt[(k + 0) * 129 + t];
            acc += hv.y * Wt[(k + 1) * 129 + t];
            acc += hv.z * Wt[(k + 2) * 129 + t];
            acc += hv.w * Wt[(k + 3) * 129 + t];
        }
        z[(size_t)i * DIM + t] = acc;

        float ev = acc * asrc;         // reduce over 128 threads -> e[i]
        #pragma unroll
        for (int o = 32; o > 0; o >>= 1) ev += __shfl_down(ev, o, 64);
        if ((t & 63) == 0) red[t >> 6] = ev;
        __syncthreads();
        if (t == 0) e[i] = red[0] + red[1];
        __syncthreads();               // guards hs/red overwrite next iter
    }
}

// ---------------------------------------------------------------------------
// CSR build, zero global atomics: per-block LDS histograms -> column sum ->
// node scan -> column exclusive scan (in place) -> LDS-ranked scatter.
// ---------------------------------------------------------------------------
__global__ __launch_bounds__(256) void hist2_kernel(
    const int* __restrict__ dst, int* __restrict__ bh)
{
    __shared__ int lh[NN];
    const int b = blockIdx.x, t = threadIdx.x;
    for (int v = t; v < NN; v += 256) lh[v] = 0;
    __syncthreads();
    const int beg = b * EPB;
    const int end = (beg + EPB < NE) ? beg + EPB : NE;
    for (int i = beg + t; i < end; i += 256) atomicAdd(&lh[dst[i]], 1);
    __syncthreads();
    for (int v = t; v < NN; v += 256) bh[b * NN + v] = lh[v];
}

__global__ void colsum_kernel(const int* __restrict__ bh, int* __restrict__ cnt)
{
    int v = blockIdx.x * blockDim.x + threadIdx.x;
    if (v < NN) {
        int s = 0;
        for (int b = 0; b < NB; ++b) s += bh[b * NN + v];
        cnt[v] = s;
    }
}

__global__ __launch_bounds__(1024) void scan_kernel(
    const int* __restrict__ cnt, int* __restrict__ offs, int* __restrict__ cur, int n)
{
    __shared__ int part[1024];
    const int t = threadIdx.x;
    constexpr int C = 10;              // 1024*10 >= 10000
    int loc[C];
    int base = t * C, s = 0;
    #pragma unroll
    for (int j = 0; j < C; ++j) {
        int idx = base + j;
        int v = (idx < n) ? cnt[idx] : 0;
        loc[j] = s; s += v;
    }
    part[t] = s;
    __syncthreads();
    for (int off = 1; off < 1024; off <<= 1) {   // Hillis-Steele inclusive scan
        int v = (t >= off) ? part[t - off] : 0;
        __syncthreads();
        if (t >= off) part[t] += v;
        __syncthreads();
    }
    int pre = (t == 0) ? 0 : part[t - 1];
    #pragma unroll
    for (int j = 0; j < C; ++j) {
        int idx = base + j;
        if (idx < n) { int o = pre + loc[j]; offs[idx] = o; cur[idx] = o; }
    }
    if (t == 1023) offs[n] = part[1023];
}

__global__ void colscan_kernel(int* __restrict__ bh, const int* __restrict__ offs)
{
    int v = blockIdx.x * blockDim.x + threadIdx.x;
    if (v < NN) {
        int run = offs[v];
        for (int b = 0; b < NB; ++b) {
            int c = bh[b * NN + v];
            bh[b * NN + v] = run;      // in-place: becomes per-(block,node) base
            run += c;
        }
    }
}

__global__ __launch_bounds__(256) void scatter2_kernel(
    const int* __restrict__ src, const int* __restrict__ dst,
    const int* __restrict__ base, int* __restrict__ esrc)
{
    __shared__ int lcur[NN];
    const int b = blockIdx.x, t = threadIdx.x;
    for (int v = t; v < NN; v += 256) lcur[v] = 0;
    __syncthreads();
    const int beg = b * EPB;
    const int end = (beg + EPB < NE) ? beg + EPB : NE;
    for (int i = beg + t; i < end; i += 256) {
        int d = dst[i];
        int lp = atomicAdd(&lcur[d], 1);           // LDS atomic only
        esrc[base[b * NN + d] + lp] = src[i];      // plain global write
    }
}

// -------- fallback CSR build (global atomics) if workspace is small --------
__global__ void hist_kernel(const int* __restrict__ dst, int* __restrict__ cnt, int n)
{
    int i = blockIdx.x * blockDim.x + threadIdx.x;
    if (i < n) atomicAdd(&cnt[dst[i]], 1);
}

__global__ void scatter_kernel(const int* __restrict__ src, const int* __restrict__ dst,
                               int* __restrict__ cur, int* __restrict__ esrc, int n)
{
    int i = blockIdx.x * blockDim.x + threadIdx.x;
    if (i < n) {
        int p = atomicAdd(&cur[dst[i]], 1);
        esrc[p] = src[i];
    }
}

// ---------------------------------------------------------------------------
// Per-node softmax + aggregate. One 128-thread block per dst node; thread t
// owns output dim t. f[dst] cancels inside the per-segment softmax.
// ---------------------------------------------------------------------------
__global__ __launch_bounds__(128) void agg_kernel(
    const int* __restrict__ offs, const int* __restrict__ esrc,
    const float* __restrict__ e, const float* __restrict__ z,
    float* __restrict__ out)
{
    __shared__ float rbuf[2];
    const int v = blockIdx.x;
    const int t = threadIdx.x;
    const int beg = offs[v], end = offs[v + 1];

    // pass 1: max of e[src] over this node's in-edges
    float lm = -3.4e38f;
    for (int i = beg + t; i < end; i += 128) lm = fmaxf(lm, e[esrc[i]]);
    #pragma unroll
    for (int o = 32; o > 0; o >>= 1) lm = fmaxf(lm, __shfl_xor(lm, o, 64));
    if ((t & 63) == 0) rbuf[t >> 6] = lm;
    __syncthreads();
    const float mx = fmaxf(rbuf[0], rbuf[1]);
    __syncthreads();

    // pass 2: denominator
    float ls = 0.f;
    for (int i = beg + t; i < end; i += 128) ls += __expf(e[esrc[i]] - mx);
    #pragma unroll
    for (int o = 32; o > 0; o >>= 1) ls += __shfl_xor(ls, o, 64);
    if ((t & 63) == 0) rbuf[t >> 6] = ls;
    __syncthreads();
    const float den = rbuf[0] + rbuf[1];
    const float inv = (den > 0.f) ? (1.f / den) : 0.f;

    // pass 3: out[v][t] = sum_i alpha_i * z[src_i][t]  (coalesced 512B row reads)
    float a0 = 0.f, a1 = 0.f, a2 = 0.f, a3 = 0.f;
    int i = beg;
    for (; i + 3 < end; i += 4) {
        int s0 = esrc[i], s1 = esrc[i + 1], s2 = esrc[i + 2], s3 = esrc[i + 3];
        float w0 = __expf(e[s0] - mx) * inv;
        float w1 = __expf(e[s1] - mx) * inv;
        float w2 = __expf(e[s2] - mx) * inv;
        float w3 = __expf(e[s3] - mx) * inv;
        a0 += w0 * z[(size_t)s0 * DIM + t];
        a1 += w1 * z[(size_t)s1 * DIM + t];
        a2 += w2 * z[(size_t)s2 * DIM + t];
        a3 += w3 * z[(size_t)s3 * DIM + t];
    }
    for (; i < end; ++i) {
        int s = esrc[i];
        a0 += __expf(e[s] - mx) * inv * z[(size_t)s * DIM + t];
    }
    out[(size_t)v * DIM + t] = (end > beg) ? ((a0 + a1) + (a2 + a3)) : 0.f;
}

// ---------------------------------------------------------------------------
extern "C" void kernel_launch(void* const* d_in, const int* in_sizes, int n_in,
                              void* d_out, int out_size, void* d_ws, size_t ws_size,
                              hipStream_t stream)
{
    const float* h     = (const float*)d_in[0];
    const int*   src   = (const int*)d_in[1];
    const int*   dst   = (const int*)d_in[2];
    const float* Wfc   = (const float*)d_in[3];
    const float* Wattn = (const float*)d_in[4];
    float* out = (float*)d_out;

    // common workspace head
    float* z    = (float*)d_ws;                 // 1,280,000 f32 (5.12 MB)
    float* e    = z + (size_t)NN * DIM;         // 10,016 f32
    int*   cnt  = (int*)(e + 10016);            // 10,016 int
    int*   offs = cnt + 10016;                  // 10,016 int

    fc_kernel<<<1024, 128, 0, stream>>>(h, Wfc, Wattn, z, e, NN);

    const size_t need_new = (size_t)(1280000 + 3 * 10016 + NB * NN + NE + 64) * 4;
    if (ws_size >= need_new) {
        // ---- atomic-free CSR build ----
        int* bh   = offs + 10016;               // NB*NN int (2.56 MB), becomes base
        int* esrc = bh + (size_t)NB * NN;       // NE int (2.56 MB)

        hist2_kernel<<<NB, 256, 0, stream>>>(dst, bh);
        colsum_kernel<<<(NN + 255) / 256, 256, 0, stream>>>(bh, cnt);
        scan_kernel<<<1, 1024, 0, stream>>>(cnt, offs, cnt, NN);  // cnt reused as dummy cur
        colscan_kernel<<<(NN + 255) / 256, 256, 0, stream>>>(bh, offs);
        scatter2_kernel<<<NB, 256, 0, stream>>>(src, dst, bh, esrc);
        agg_kernel<<<NN, 128, 0, stream>>>(offs, esrc, e, z, out);
    } else {
        // ---- fallback: global-atomic CSR build (fits ~8 MB) ----
        int* cur  = offs + 10016;               // 10,016 int
        int* esrc = cur + 10016;                // NE int

        hipMemsetAsync(cnt, 0, NN * sizeof(int), stream);
        hist_kernel<<<(NE + 255) / 256, 256, 0, stream>>>(dst, cnt, NE);
        scan_kernel<<<1, 1024, 0, stream>>>(cnt, offs, cur, NN);
        scatter_kernel<<<(NE + 255) / 256, 256, 0, stream>>>(src, dst, cur, esrc, NE);
        agg_kernel<<<NN, 128, 0, stream>>>(offs, esrc, e, z, out);
    }
}

// Round 3
// 94.972 us; speedup vs baseline: 1.8995x; 1.5106x over previous
//
#include <hip/hip_runtime.h>

#define NN 10000
#define NE 640000
#define DIM 128
#define NB 128                        // histogram blocks for CSR build
#define EPB ((NE + NB - 1) / NB)      // edges per block = 5000
#define FCN 32                        // nodes per fc block

static __device__ __forceinline__ unsigned short f2bf(float f) {
    unsigned u = __float_as_uint(f);
    unsigned r = (u + 0x7FFFu + ((u >> 16) & 1u)) >> 16;   // RNE
    return (unsigned short)r;
}

// ---------------------------------------------------------------------------
// Wt[k][j] = W[j][k]  (64 KB, stays L2-resident, shared by all fc blocks)
// ---------------------------------------------------------------------------
__global__ void transpose_kernel(const float* __restrict__ W, float* __restrict__ Wt)
{
    int idx = blockIdx.x * 256 + threadIdx.x;      // 64 blocks x 256 = 16384
    int j = idx >> 7, k = idx & 127;
    Wt[k * 128 + j] = W[idx];
}

// ---------------------------------------------------------------------------
// z = h @ W^T via register tiles. Block: 256 thr, 32 nodes.
// Thread (jl = t&31, ng = t>>5) owns j in [4*jl, 4*jl+4) x i in [4*ng, 4*ng+4).
// Also emits z_bf16 (gather payload) and e[i] = z[i,:] . a_src.
// ---------------------------------------------------------------------------
__global__ __launch_bounds__(256) void fc2_kernel(
    const float* __restrict__ h, const float* __restrict__ Wt,
    const float* __restrict__ Wa, float* __restrict__ z,
    unsigned short* __restrict__ zb, float* __restrict__ e, int n)
{
    __shared__ float hs[FCN][DIM];                 // 16 KB
    const int t  = threadIdx.x;
    const int jl = t & 31, jq = jl * 4;
    const int ng = t >> 5;
    const int i0 = blockIdx.x * FCN;

    // stage h tile (zero-fill OOB rows)
    const float4* h4 = (const float4*)h;
    float4* hs4 = (float4*)hs;
    for (int u = t; u < FCN * 32; u += 256) {
        int row = u >> 5, gi = i0 + row;
        hs4[u] = (gi < n) ? h4[(size_t)gi * 32 + (u & 31)]
                          : make_float4(0.f, 0.f, 0.f, 0.f);
    }
    __syncthreads();

    float acc[4][4] = {};
    for (int k = 0; k < DIM; k += 4) {
        float4 wv[4];
        #pragma unroll
        for (int kk = 0; kk < 4; ++kk)
            wv[kk] = *(const float4*)&Wt[(k + kk) * DIM + jq];
        const float* wf = (const float*)wv;        // [kk*4 + jm]
        #pragma unroll
        for (int m = 0; m < 4; ++m) {
            float4 hv = *(const float4*)&hs[4 * ng + m][k];
            float hvf[4] = {hv.x, hv.y, hv.z, hv.w};
            #pragma unroll
            for (int kk = 0; kk < 4; ++kk)
                #pragma unroll
                for (int jm = 0; jm < 4; ++jm)
                    acc[m][jm] += hvf[kk] * wf[kk * 4 + jm];
        }
    }

    const float a0 = Wa[jq], a1 = Wa[jq + 1], a2 = Wa[jq + 2], a3 = Wa[jq + 3];
    #pragma unroll
    for (int m = 0; m < 4; ++m) {
        int gi = i0 + 4 * ng + m;
        float ep = acc[m][0] * a0 + acc[m][1] * a1 + acc[m][2] * a2 + acc[m][3] * a3;
        #pragma unroll
        for (int o = 16; o > 0; o >>= 1) ep += __shfl_xor(ep, o, 64);
        if (gi < n) {
            *(float4*)&z[(size_t)gi * DIM + jq] =
                make_float4(acc[m][0], acc[m][1], acc[m][2], acc[m][3]);
            ushort4 zo;
            zo.x = f2bf(acc[m][0]); zo.y = f2bf(acc[m][1]);
            zo.z = f2bf(acc[m][2]); zo.w = f2bf(acc[m][3]);
            *(ushort4*)&zb[(size_t)gi * DIM + jq] = zo;
            if (jl == 0) e[gi] = ep;
        }
    }
}

// ---------------------------------------------------------------------------
// CSR build, zero global atomics.
// ---------------------------------------------------------------------------
__global__ __launch_bounds__(256) void hist2_kernel(
    const int* __restrict__ dst, int* __restrict__ bh)
{
    __shared__ int lh[NN];
    const int b = blockIdx.x, t = threadIdx.x;
    for (int v = t; v < NN; v += 256) lh[v] = 0;
    __syncthreads();
    const int beg = b * EPB;
    const int end = (beg + EPB < NE) ? beg + EPB : NE;
    for (int i = beg + t; i < end; i += 256) atomicAdd(&lh[dst[i]], 1);
    __syncthreads();
    for (int v = t; v < NN; v += 256) bh[(size_t)b * NN + v] = lh[v];
}

__global__ void colsum_kernel(const int* __restrict__ bh, int* __restrict__ cnt)
{
    int v = blockIdx.x * blockDim.x + threadIdx.x;
    if (v < NN) {
        int s = 0;
        for (int b = 0; b < NB; ++b) s += bh[(size_t)b * NN + v];
        cnt[v] = s;
    }
}

// wave-shuffle scan: 1024 thr x C=10 items, 2 barriers total
__global__ __launch_bounds__(1024) void scan_kernel(
    const int* __restrict__ cnt, int* __restrict__ offs, int n)
{
    __shared__ int wsum[16];
    const int t = threadIdx.x, lane = t & 63, wid = t >> 6;
    constexpr int C = 10;
    int loc[C];
    int base = t * C, s = 0;
    #pragma unroll
    for (int j = 0; j < C; ++j) {
        int idx = base + j;
        int v = (idx < n) ? cnt[idx] : 0;
        loc[j] = s; s += v;
    }
    int x = s;
    #pragma unroll
    for (int off = 1; off <= 32; off <<= 1) {
        int y = __shfl_up(x, off, 64);
        if (lane >= off) x += y;
    }
    if (lane == 63) wsum[wid] = x;
    __syncthreads();
    if (t < 16) {
        int w = wsum[t];
        #pragma unroll
        for (int off = 1; off <= 8; off <<= 1) {
            int y = __shfl_up(w, off, 64);
            if (t >= off) w += y;
        }
        wsum[t] = w;                   // inclusive wave sums
    }
    __syncthreads();
    int wbase = (wid == 0) ? 0 : wsum[wid - 1];
    int excl = wbase + (x - s);
    #pragma unroll
    for (int j = 0; j < C; ++j) {
        int idx = base + j;
        if (idx < n) offs[idx] = excl + loc[j];
    }
    if (t == 0) offs[n] = wsum[15];
}

__global__ void colscan_kernel(int* __restrict__ bh, const int* __restrict__ offs)
{
    int v = blockIdx.x * blockDim.x + threadIdx.x;
    if (v < NN) {
        int run = offs[v];
        for (int b = 0; b < NB; ++b) {
            int c = bh[(size_t)b * NN + v];
            bh[(size_t)b * NN + v] = run;
            run += c;
        }
    }
}

__global__ __launch_bounds__(256) void scatter2_kernel(
    const int* __restrict__ src, const int* __restrict__ dst,
    const int* __restrict__ base, int* __restrict__ esrc)
{
    __shared__ int lcur[NN];
    const int b = blockIdx.x, t = threadIdx.x;
    for (int v = t; v < NN; v += 256) lcur[v] = 0;
    __syncthreads();
    const int beg = b * EPB;
    const int end = (beg + EPB < NE) ? beg + EPB : NE;
    for (int i = beg + t; i < end; i += 256) {
        int d = dst[i];
        int lp = atomicAdd(&lcur[d], 1);               // LDS atomic only
        esrc[base[(size_t)b * NN + d] + lp] = src[i];  // plain global write
    }
}

// ---------------------------------------------------------------------------
// Per-node softmax + aggregate. Block = dst node, thread t owns dim t.
// z gathered in bf16 (2.56 MB -> per-XCD-L2-resident); alpha from fp32 e.
// ---------------------------------------------------------------------------
#define DEGCAP 1024
__global__ __launch_bounds__(128) void agg_kernel(
    const int* __restrict__ offs, const int* __restrict__ esrc,
    const float* __restrict__ e, const unsigned short* __restrict__ zb,
    float* __restrict__ out)
{
    __shared__ float rbuf[2];
    __shared__ int   es[DEGCAP];
    __shared__ float ew[DEGCAP];
    const int v = blockIdx.x, t = threadIdx.x;
    const int beg = offs[v], end = offs[v + 1];
    const int deg = end - beg;

    if (deg <= DEGCAP) {
        // pass 1: cache src ids, find max e
        float lm = -3.4e38f;
        for (int i = t; i < deg; i += 128) {
            int s = esrc[beg + i];
            es[i] = s;
            lm = fmaxf(lm, e[s]);
        }
        #pragma unroll
        for (int o = 32; o > 0; o >>= 1) lm = fmaxf(lm, __shfl_xor(lm, o, 64));
        if ((t & 63) == 0) rbuf[t >> 6] = lm;
        __syncthreads();
        const float mx = fmaxf(rbuf[0], rbuf[1]);
        __syncthreads();

        // pass 2: weights into LDS, denominator
        float ls = 0.f;
        for (int i = t; i < deg; i += 128) {
            float w = __expf(e[es[i]] - mx);
            ew[i] = w; ls += w;
        }
        #pragma unroll
        for (int o = 32; o > 0; o >>= 1) ls += __shfl_xor(ls, o, 64);
        if ((t & 63) == 0) rbuf[t >> 6] = ls;
        __syncthreads();
        const float den = rbuf[0] + rbuf[1];
        const float inv = (den > 0.f) ? (1.f / den) : 0.f;

        // pass 3: weighted bf16 row gather
        float a0 = 0.f, a1 = 0.f, a2 = 0.f, a3 = 0.f;
        int i = 0;
        for (; i + 3 < deg; i += 4) {
            int s0 = es[i], s1 = es[i + 1], s2 = es[i + 2], s3 = es[i + 3];
            a0 += ew[i]     * __uint_as_float((unsigned)zb[(size_t)s0 * DIM + t] << 16);
            a1 += ew[i + 1] * __uint_as_float((unsigned)zb[(size_t)s1 * DIM + t] << 16);
            a2 += ew[i + 2] * __uint_as_float((unsigned)zb[(size_t)s2 * DIM + t] << 16);
            a3 += ew[i + 3] * __uint_as_float((unsigned)zb[(size_t)s3 * DIM + t] << 16);
        }
        for (; i < deg; ++i)
            a0 += ew[i] * __uint_as_float((unsigned)zb[(size_t)es[i] * DIM + t] << 16);
        out[(size_t)v * DIM + t] = (deg > 0) ? ((a0 + a1) + (a2 + a3)) * inv : 0.f;
    } else {
        // fallback (never expected at avg deg 64): recompute path
        float lm = -3.4e38f;
        for (int i = beg + t; i < end; i += 128) lm = fmaxf(lm, e[esrc[i]]);
        #pragma unroll
        for (int o = 32; o > 0; o >>= 1) lm = fmaxf(lm, __shfl_xor(lm, o, 64));
        if ((t & 63) == 0) rbuf[t >> 6] = lm;
        __syncthreads();
        const float mx = fmaxf(rbuf[0], rbuf[1]);
        __syncthreads();
        float ls = 0.f;
        for (int i = beg + t; i < end; i += 128) ls += __expf(e[esrc[i]] - mx);
        #pragma unroll
        for (int o = 32; o > 0; o >>= 1) ls += __shfl_xor(ls, o, 64);
        if ((t & 63) == 0) rbuf[t >> 6] = ls;
        __syncthreads();
        const float den = rbuf[0] + rbuf[1];
        const float inv = (den > 0.f) ? (1.f / den) : 0.f;
        float a = 0.f;
        for (int i = beg; i < end; ++i) {
            int s = esrc[i];
            a += __expf(e[s] - mx) * __uint_as_float((unsigned)zb[(size_t)s * DIM + t] << 16);
        }
        out[(size_t)v * DIM + t] = a * inv;
    }
}

// ---------------------------------------------------------------------------
extern "C" void kernel_launch(void* const* d_in, const int* in_sizes, int n_in,
                              void* d_out, int out_size, void* d_ws, size_t ws_size,
                              hipStream_t stream)
{
    const float* h     = (const float*)d_in[0];
    const int*   src   = (const int*)d_in[1];
    const int*   dst   = (const int*)d_in[2];
    const float* Wfc   = (const float*)d_in[3];
    const float* Wattn = (const float*)d_in[4];
    float* out = (float*)d_out;

    // workspace layout (f32 slots): ~20.3 MB total (ws observed ~268 MB)
    float*          z    = (float*)d_ws;              // 1,280,000
    unsigned short* zb   = (unsigned short*)(z + 1280000);  // 640,000 slots
    float*          e    = (float*)(zb + 1280000);    // 10,016
    int*            cnt  = (int*)(e + 10016);         // 10,016
    int*            offs = cnt + 10016;               // 10,016
    float*          Wt   = (float*)(offs + 10016);    // 16,384
    int*            bh   = (int*)(Wt + 16384);        // NB*NN = 1,280,000
    int*            esrc = bh + (size_t)NB * NN;      // 640,000

    transpose_kernel<<<64, 256, 0, stream>>>(Wfc, Wt);
    fc2_kernel<<<(NN + FCN - 1) / FCN, 256, 0, stream>>>(h, Wt, Wattn, z, zb, e, NN);
    hist2_kernel<<<NB, 256, 0, stream>>>(dst, bh);
    colsum_kernel<<<(NN + 255) / 256, 256, 0, stream>>>(bh, cnt);
    scan_kernel<<<1, 1024, 0, stream>>>(cnt, offs, NN);
    colscan_kernel<<<(NN + 255) / 256, 256, 0, stream>>>(bh, offs);
    scatter2_kernel<<<NB, 256, 0, stream>>>(src, dst, bh, esrc);
    agg_kernel<<<NN, 128, 0, stream>>>(offs, esrc, e, zb, out);
}

// Round 4
// 86.907 us; speedup vs baseline: 2.0758x; 1.0928x over previous
//
#include <hip/hip_runtime.h>

#define NN 10000
#define NE 640000
#define DIM 128
#define NB 125                        // histogram blocks (NE = NB*EPB exactly)
#define EPB 5120                      // edges per block, int4-aligned
#define FCN 32                        // nodes per fc block
#define DEGCAP 512                    // in-LDS degree cap for agg fast path

static __device__ __forceinline__ unsigned short f2bf(float f) {
    unsigned u = __float_as_uint(f);
    unsigned r = (u + 0x7FFFu + ((u >> 16) & 1u)) >> 16;   // RNE
    return (unsigned short)r;
}

// ---------------------------------------------------------------------------
// Per-block LDS histogram of dst  (+ fused W transpose: 132 elems/block)
// ---------------------------------------------------------------------------
__global__ __launch_bounds__(256) void hist2T_kernel(
    const int* __restrict__ dst, int* __restrict__ bh,
    const float* __restrict__ W, float* __restrict__ Wt)
{
    __shared__ int lh[NN];
    const int b = blockIdx.x, t = threadIdx.x;
    for (int v = t; v < NN; v += 256) lh[v] = 0;
    // fused transpose: Wt[k][j] = W[j][k]
    for (int u = t; u < 132; u += 256) {
        int idx = b * 132 + u;
        if (idx < DIM * DIM) Wt[(idx & 127) * DIM + (idx >> 7)] = W[idx];
    }
    __syncthreads();
    const int4* d4 = (const int4*)(dst + b * EPB);
    for (int i = t; i < EPB / 4; i += 256) {
        int4 d = d4[i];
        atomicAdd(&lh[d.x], 1); atomicAdd(&lh[d.y], 1);
        atomicAdd(&lh[d.z], 1); atomicAdd(&lh[d.w], 1);
    }
    __syncthreads();
    for (int v = t; v < NN; v += 256) bh[(size_t)b * NN + v] = lh[v];
}

// ---------------------------------------------------------------------------
// z(bf16) = h @ W^T ; e[i] = z[i,:] . a_src.  Register 4x4 tiles, Wt from L2.
// ---------------------------------------------------------------------------
__global__ __launch_bounds__(256) void fc3_kernel(
    const float* __restrict__ h, const float* __restrict__ Wt,
    const float* __restrict__ Wa, unsigned short* __restrict__ zb,
    float* __restrict__ e, int n)
{
    __shared__ float hs[FCN][DIM];                 // 16 KB
    const int t  = threadIdx.x;
    const int jl = t & 31, jq = jl * 4;
    const int ng = t >> 5;
    const int i0 = blockIdx.x * FCN;

    const float4* h4 = (const float4*)h;
    float4* hs4 = (float4*)hs;
    for (int u = t; u < FCN * 32; u += 256) {
        int row = u >> 5, gi = i0 + row;
        hs4[u] = (gi < n) ? h4[(size_t)gi * 32 + (u & 31)]
                          : make_float4(0.f, 0.f, 0.f, 0.f);
    }
    __syncthreads();

    float acc[4][4] = {};
    for (int k = 0; k < DIM; k += 4) {
        float4 wv[4];
        #pragma unroll
        for (int kk = 0; kk < 4; ++kk)
            wv[kk] = *(const float4*)&Wt[(k + kk) * DIM + jq];
        const float* wf = (const float*)wv;        // [kk*4 + jm]
        #pragma unroll
        for (int m = 0; m < 4; ++m) {
            float4 hv = *(const float4*)&hs[4 * ng + m][k];
            float hvf[4] = {hv.x, hv.y, hv.z, hv.w};
            #pragma unroll
            for (int kk = 0; kk < 4; ++kk)
                #pragma unroll
                for (int jm = 0; jm < 4; ++jm)
                    acc[m][jm] += hvf[kk] * wf[kk * 4 + jm];
        }
    }

    const float a0 = Wa[jq], a1 = Wa[jq + 1], a2 = Wa[jq + 2], a3 = Wa[jq + 3];
    #pragma unroll
    for (int m = 0; m < 4; ++m) {
        int gi = i0 + 4 * ng + m;
        float ep = acc[m][0] * a0 + acc[m][1] * a1 + acc[m][2] * a2 + acc[m][3] * a3;
        #pragma unroll
        for (int o = 16; o > 0; o >>= 1) ep += __shfl_xor(ep, o, 64);
        if (gi < n) {
            ushort4 zo;
            zo.x = f2bf(acc[m][0]); zo.y = f2bf(acc[m][1]);
            zo.z = f2bf(acc[m][2]); zo.w = f2bf(acc[m][3]);
            *(ushort4*)&zb[(size_t)gi * DIM + jq] = zo;
            if (jl == 0) e[gi] = ep;
        }
    }
}

// ---------------------------------------------------------------------------
// Fused colsum+colscan: bh column -> exclusive per-block bases (in place),
// total -> cnt[v].  One 5.12MB read+write pass instead of two reads + write.
// ---------------------------------------------------------------------------
__global__ void colscan0_kernel(int* __restrict__ bh, int* __restrict__ cnt)
{
    int v = blockIdx.x * blockDim.x + threadIdx.x;
    if (v < NN) {
        int run = 0;
        #pragma unroll 5
        for (int b = 0; b < NB; ++b) {
            int c = bh[(size_t)b * NN + v];
            bh[(size_t)b * NN + v] = run;
            run += c;
        }
        cnt[v] = run;
    }
}

// wave-shuffle exclusive scan of cnt -> offs (1 block, 2 barriers)
__global__ __launch_bounds__(1024) void scan_kernel(
    const int* __restrict__ cnt, int* __restrict__ offs, int n)
{
    __shared__ int wsum[16];
    const int t = threadIdx.x, lane = t & 63, wid = t >> 6;
    constexpr int C = 10;
    int loc[C];
    int base = t * C, s = 0;
    #pragma unroll
    for (int j = 0; j < C; ++j) {
        int idx = base + j;
        int v = (idx < n) ? cnt[idx] : 0;
        loc[j] = s; s += v;
    }
    int x = s;
    #pragma unroll
    for (int off = 1; off <= 32; off <<= 1) {
        int y = __shfl_up(x, off, 64);
        if (lane >= off) x += y;
    }
    if (lane == 63) wsum[wid] = x;
    __syncthreads();
    if (t < 16) {
        int w = wsum[t];
        #pragma unroll
        for (int off = 1; off <= 8; off <<= 1) {
            int y = __shfl_up(w, off, 64);
            if (t >= off) w += y;
        }
        wsum[t] = w;
    }
    __syncthreads();
    int wbase = (wid == 0) ? 0 : wsum[wid - 1];
    int excl = wbase + (x - s);
    #pragma unroll
    for (int j = 0; j < C; ++j) {
        int idx = base + j;
        if (idx < n) offs[idx] = excl + loc[j];
    }
    if (t == 0) offs[n] = wsum[15];
}

// ---------------------------------------------------------------------------
// LDS-ranked scatter: esrc[offs[d] + bh[b][d] + local_rank] = src
// ---------------------------------------------------------------------------
__global__ __launch_bounds__(256) void scatter2_kernel(
    const int* __restrict__ src, const int* __restrict__ dst,
    const int* __restrict__ base, const int* __restrict__ offs,
    int* __restrict__ esrc)
{
    __shared__ int lcur[NN];
    const int b = blockIdx.x, t = threadIdx.x;
    for (int v = t; v < NN; v += 256) lcur[v] = 0;
    __syncthreads();
    const int4* d4 = (const int4*)(dst + b * EPB);
    const int4* s4 = (const int4*)(src + b * EPB);
    const int* brow = base + (size_t)b * NN;
    for (int i = t; i < EPB / 4; i += 256) {
        int4 d = d4[i]; int4 s = s4[i];
        int lp;
        lp = atomicAdd(&lcur[d.x], 1); esrc[offs[d.x] + brow[d.x] + lp] = s.x;
        lp = atomicAdd(&lcur[d.y], 1); esrc[offs[d.y] + brow[d.y] + lp] = s.y;
        lp = atomicAdd(&lcur[d.z], 1); esrc[offs[d.z] + brow[d.z] + lp] = s.z;
        lp = atomicAdd(&lcur[d.w], 1); esrc[offs[d.w] + brow[d.w] + lp] = s.w;
    }
}

// ---------------------------------------------------------------------------
// Softmax + aggregate: 1 wave per dst node, thread t owns dims {2t, 2t+1}
// via one uint (bf16x2) load -> 256B/wave/edge in a single instruction.
// Single-wave shuffle reductions: one barrier total.
// ---------------------------------------------------------------------------
__global__ __launch_bounds__(64) void agg64_kernel(
    const int* __restrict__ offs, const int* __restrict__ esrc,
    const float* __restrict__ e, const unsigned* __restrict__ zb32,
    float* __restrict__ out)
{
    __shared__ int   es[DEGCAP];
    __shared__ float ew[DEGCAP];
    const int v = blockIdx.x, t = threadIdx.x;
    const int beg = offs[v], end = offs[v + 1];
    const int deg = end - beg;

    if (deg <= DEGCAP) {
        float lm = -3.4e38f;
        for (int i = t; i < deg; i += 64) {
            int s = esrc[beg + i];
            es[i] = s;
            lm = fmaxf(lm, e[s]);
        }
        #pragma unroll
        for (int o = 32; o > 0; o >>= 1) lm = fmaxf(lm, __shfl_xor(lm, o, 64));

        float ls = 0.f;
        for (int i = t; i < deg; i += 64) {
            float w = __expf(e[es[i]] - lm);       // es[i] written by this lane
            ew[i] = w; ls += w;
        }
        #pragma unroll
        for (int o = 32; o > 0; o >>= 1) ls += __shfl_xor(ls, o, 64);
        const float inv = (ls > 0.f) ? (1.f / ls) : 0.f;
        __syncthreads();                           // es/ew visible cross-lane

        float a0 = 0.f, a1 = 0.f, a2 = 0.f, a3 = 0.f;
        int i = 0;
        for (; i + 1 < deg; i += 2) {
            unsigned u0 = zb32[(size_t)es[i]     * 64 + t];
            unsigned u1 = zb32[(size_t)es[i + 1] * 64 + t];
            float w0 = ew[i], w1 = ew[i + 1];
            a0 += w0 * __uint_as_float(u0 << 16);
            a1 += w0 * __uint_as_float(u0 & 0xFFFF0000u);
            a2 += w1 * __uint_as_float(u1 << 16);
            a3 += w1 * __uint_as_float(u1 & 0xFFFF0000u);
        }
        if (i < deg) {
            unsigned u = zb32[(size_t)es[i] * 64 + t];
            float w = ew[i];
            a0 += w * __uint_as_float(u << 16);
            a1 += w * __uint_as_float(u & 0xFFFF0000u);
        }
        float2 r;
        r.x = (a0 + a2) * inv;
        r.y = (a1 + a3) * inv;
        *(float2*)&out[(size_t)v * DIM + 2 * t] = r;
    } else {
        // fallback (deg > 512; not expected at avg deg 64)
        float lm = -3.4e38f;
        for (int i = beg + t; i < end; i += 64) lm = fmaxf(lm, e[esrc[i]]);
        #pragma unroll
        for (int o = 32; o > 0; o >>= 1) lm = fmaxf(lm, __shfl_xor(lm, o, 64));
        float ls = 0.f;
        for (int i = beg + t; i < end; i += 64) ls += __expf(e[esrc[i]] - lm);
        #pragma unroll
        for (int o = 32; o > 0; o >>= 1) ls += __shfl_xor(ls, o, 64);
        const float inv = (ls > 0.f) ? (1.f / ls) : 0.f;
        float a0 = 0.f, a1 = 0.f;
        for (int i = beg; i < end; ++i) {
            int s = esrc[i];
            float w = __expf(e[s] - lm);
            unsigned u = zb32[(size_t)s * 64 + t];
            a0 += w * __uint_as_float(u << 16);
            a1 += w * __uint_as_float(u & 0xFFFF0000u);
        }
        float2 r;
        r.x = a0 * inv;
        r.y = a1 * inv;
        *(float2*)&out[(size_t)v * DIM + 2 * t] = r;
    }
}

// ---------------------------------------------------------------------------
extern "C" void kernel_launch(void* const* d_in, const int* in_sizes, int n_in,
                              void* d_out, int out_size, void* d_ws, size_t ws_size,
                              hipStream_t stream)
{
    const float* h     = (const float*)d_in[0];
    const int*   src   = (const int*)d_in[1];
    const int*   dst   = (const int*)d_in[2];
    const float* Wfc   = (const float*)d_in[3];
    const float* Wattn = (const float*)d_in[4];
    float* out = (float*)d_out;

    // workspace layout: ~10.7 MB
    unsigned short* zb   = (unsigned short*)d_ws;     // NN*DIM ushort (2.56 MB)
    float*          e    = (float*)(zb + (size_t)NN * DIM + 16);
    int*            cnt  = (int*)(e + 10016);
    int*            offs = cnt + 10016;
    float*          Wt   = (float*)(offs + 10016);    // 16,384 f32
    int*            bh   = (int*)(Wt + 16384);        // NB*NN int (5 MB)
    int*            esrc = bh + (size_t)NB * NN;      // NE int (2.56 MB)

    hist2T_kernel<<<NB, 256, 0, stream>>>(dst, bh, Wfc, Wt);
    fc3_kernel<<<(NN + FCN - 1) / FCN, 256, 0, stream>>>(h, Wt, Wattn, zb, e, NN);
    colscan0_kernel<<<(NN + 255) / 256, 256, 0, stream>>>(bh, cnt);
    scan_kernel<<<1, 1024, 0, stream>>>(cnt, offs, NN);
    scatter2_kernel<<<NB, 256, 0, stream>>>(src, dst, bh, offs, esrc);
    agg64_kernel<<<NN, 64, 0, stream>>>(offs, esrc, e, (const unsigned*)zb, out);
}